// Round 1
// 1048.397 us; speedup vs baseline: 1.2498x; 1.2498x over previous
//
#include <hip/hip_runtime.h>
#include <hip/hip_bf16.h>

// ---------------------------------------------------------------------------
// QuadrupletInteraction (GemNet-style), MI355X / gfx950.
// Pipeline: k0 (bf16 prep: m, Wdb^T, rad-pad, Wrbf^T) -> k1 (m@W_db fused rbf,
// global_load_lds + XOR-swizzle MFMA GEMM) -> k2 (down-proj) -> k3 (cbf mul +
// edge->trip gather) -> k4 (ragged bilinear) -> k5 (up-projections + swap).
// Scratch plan:
//   d_out (204.8 MB): m_bf16 [100096][512] during k0..k1; k5 overwrites last.
//   ws tt-region (written by k3 only AFTER k1): WdbT | radp | WrbfT (13.4 MB).
// Error budget: bf16-rounded GEMM inputs, f32 accumulation everywhere.
// ---------------------------------------------------------------------------

constexpr int NE   = 100000;   // edges
constexpr int NEP  = 100096;   // 782*128, row-padded (guard-free staging)
constexpr int ED   = 512;      // E
constexpr int NT   = 1000000;  // triplets
constexpr int NQ   = 2000000;  // quadruplets
constexpr int QI   = 32;       // QIN
constexpr int QO   = 32;       // QOUT
constexpr int RBF_ = 16;
constexpr int CBF_ = 16;
constexpr int SBF_ = 32;
constexpr int NSPH_= 7;
constexpr int KAVG_= 20;

typedef float f32x4 __attribute__((ext_vector_type(4)));
typedef __bf16 bf16x8 __attribute__((ext_vector_type(8)));
typedef __bf16 bf16x4 __attribute__((ext_vector_type(4)));

__device__ __forceinline__ float silu_f(float v) {
    return __fdividef(v, 1.0f + __expf(-v));
}

// async global->LDS, 16B per lane; LDS dest is wave-uniform base + lane*16
__device__ __forceinline__ void gload_lds16(const __bf16* g, __bf16* l) {
    __builtin_amdgcn_global_load_lds(
        (const __attribute__((address_space(1))) void*)g,
        (__attribute__((address_space(3))) void*)l, 16, 0, 0);
}

// ---------------- k0: bf16 prep ---------------------------------------------
// blocks [0,1600)    : mB[NEP][512] = bf16(m), pad rows zeroed
// blocks [1600,1664) : WdbT[512][512] = bf16(Wdb^T)   (64x64 LDS tiles)
// blocks [1664,2064) : radp[NEP][64]  = bf16(rad) cols<16, else 0; pad rows 0
// blocks [2064,2080) : WrbfT[512][64] = bf16(Wrbf^T) rows k<16, else 0
__global__ __launch_bounds__(256) void k0(const float* __restrict__ mM,
                                          const float* __restrict__ Wdb,
                                          const float* __restrict__ rad,
                                          const float* __restrict__ Wrbf,
                                          __bf16* __restrict__ mB,
                                          __bf16* __restrict__ WdbT,
                                          __bf16* __restrict__ radp,
                                          __bf16* __restrict__ WrbfT)
{
    const int b = blockIdx.x, tid = threadIdx.x;
    if (b < 1600) {
        const long total = (long)NEP * ED / 8;   // 6,406,144 chunks of 8
        for (long g = (long)b * 256 + tid; g < total; g += 409600L) {
            const long e0 = g * 8;
            const int row = (int)(e0 >> 9);
            bf16x8 o;
            if (row < NE) {
                const float4 v0 = *(const float4*)(mM + e0);
                const float4 v1 = *(const float4*)(mM + e0 + 4);
                o[0] = (__bf16)v0.x; o[1] = (__bf16)v0.y;
                o[2] = (__bf16)v0.z; o[3] = (__bf16)v0.w;
                o[4] = (__bf16)v1.x; o[5] = (__bf16)v1.y;
                o[6] = (__bf16)v1.z; o[7] = (__bf16)v1.w;
            } else {
#pragma unroll
                for (int j = 0; j < 8; j++) o[j] = (__bf16)0.f;
            }
            *(bf16x8*)(mB + e0) = o;
        }
    } else if (b < 1664) {
        __shared__ float tle[64 * 65];
        const int idx = b - 1600;
        const int kb = (idx >> 3) * 64, nb = (idx & 7) * 64;
#pragma unroll
        for (int f = tid; f < 1024; f += 256) {
            const int kk = f >> 4, n4 = (f & 15) * 4;
            const float4 v = *(const float4*)(Wdb + (size_t)(kb + kk) * ED + nb + n4);
            tle[(n4 + 0) * 65 + kk] = v.x;
            tle[(n4 + 1) * 65 + kk] = v.y;
            tle[(n4 + 2) * 65 + kk] = v.z;
            tle[(n4 + 3) * 65 + kk] = v.w;
        }
        __syncthreads();
#pragma unroll
        for (int f = tid; f < 1024; f += 256) {
            const int nn = f >> 4, k4 = (f & 15) * 4;
            bf16x4 o;
            o[0] = (__bf16)tle[nn * 65 + k4 + 0];
            o[1] = (__bf16)tle[nn * 65 + k4 + 1];
            o[2] = (__bf16)tle[nn * 65 + k4 + 2];
            o[3] = (__bf16)tle[nn * 65 + k4 + 3];
            *(bf16x4*)(WdbT + (size_t)(nb + nn) * ED + kb + k4) = o;
        }
    } else if (b < 2064) {
        for (int g = (b - 1664) * 256 + tid; g < NEP * 8; g += 102400) {
            const int row = g >> 3, c = g & 7;
            bf16x8 o;
            if (row < NE && c < 2) {
                const float* s = rad + (size_t)row * RBF_ + c * 8;
                const float4 v0 = *(const float4*)s;
                const float4 v1 = *(const float4*)(s + 4);
                o[0] = (__bf16)v0.x; o[1] = (__bf16)v0.y;
                o[2] = (__bf16)v0.z; o[3] = (__bf16)v0.w;
                o[4] = (__bf16)v1.x; o[5] = (__bf16)v1.y;
                o[6] = (__bf16)v1.z; o[7] = (__bf16)v1.w;
            } else {
#pragma unroll
                for (int j = 0; j < 8; j++) o[j] = (__bf16)0.f;
            }
            *(bf16x8*)(radp + (size_t)row * 64 + c * 8) = o;
        }
    } else {
        for (int f = (b - 2064) * 256 + tid; f < 512 * 64; f += 4096) {
            const int n = f >> 6, k = f & 63;
            const float v = (k < RBF_) ? Wrbf[(size_t)k * ED + n] : 0.f;
            WrbfT[(size_t)n * 64 + k] = (__bf16)v;
        }
    }
}

// ---------------- k1: x1 = bf16( silu(m@W_db) * (rad@W_rbf) * s_rbf ) -------
// m97-structure GEMM: 128x128 tile, BK=64, global_load_lds width-16 staging.
// LDS tiles As/Bs: row-major [128][64] bf16 (128 B rows), 16-B chunk XOR-
// swizzled by (row&7). Swizzle applied on BOTH sides (rule #21): linear LDS
// dest + inverse-swizzled global source in staging, same XOR on ds_read.
// Read conflicts: 16 lanes -> 8 distinct 16-B slots -> 2-way = free (m136).
__global__ __launch_bounds__(256) void k1(const __bf16* __restrict__ mB,
                                          const __bf16* __restrict__ WdbT,
                                          const __bf16* __restrict__ radp,
                                          const __bf16* __restrict__ WrbfT,
                                          const float* __restrict__ s_rbf,
                                          __bf16* __restrict__ x1)
{
    __shared__ __align__(16) __bf16 As[128 * 64];
    __shared__ __align__(16) __bf16 Bs[128 * 64];

    const int tid  = threadIdx.x;
    const int lane = tid & 63, wv = tid >> 6;
    const int ml = lane & 15, qd = lane >> 4;
    const int col0 = blockIdx.x * 128;   // 4 col-blocks (adjacent dispatch -> A reuse in L2)
    const int row0 = blockIdx.y * 128;   // 782 row-blocks
    const int wm = (wv >> 1) * 64, wn = (wv & 1) * 64;

    // staging geometry: inst i covers LDS bytes [i*1024,(i+1)*1024) = tile
    // rows i*8..i*8+7; lane l -> row i*8+(l>>3), dest chunk l&7, source chunk
    // XOR-swizzled by row&7 (= l>>3 since i*8 == 0 mod 8).
    const int sr  = lane >> 3;
    const int scs = (lane & 7) ^ sr;     // pre-swizzled source chunk
    const int swr = ml & 7;              // read-side XOR (row&7 == ml&7)

    f32x4 acc[4][4], accR[4][4];
    const f32x4 vz = {0.f, 0.f, 0.f, 0.f};
#pragma unroll
    for (int i = 0; i < 4; i++)
#pragma unroll
        for (int j = 0; j < 4; j++) { acc[i][j] = vz; accR[i][j] = vz; }

    const __bf16* aT = mB    + (size_t)row0 * ED;
    const __bf16* bT = WdbT  + (size_t)col0 * ED;
    const __bf16* aR = radp  + (size_t)row0 * 64;
    const __bf16* bR = WrbfT + (size_t)col0 * 64;

    for (int k0 = 0; k0 < ED; k0 += 64) {
        __syncthreads();   // previous compute's ds_reads drained before overwrite
#pragma unroll
        for (int j = 0; j < 4; j++) {
            const int i = wv * 4 + j;
            const int r = i * 8 + sr;
            gload_lds16(aT + (size_t)r * ED + k0 + scs * 8, &As[i * 512]);
            gload_lds16(bT + (size_t)r * ED + k0 + scs * 8, &Bs[i * 512]);
        }
        __syncthreads();   // compiler emits vmcnt(0) before barrier -> tiles ready
#pragma unroll
        for (int kk = 0; kk < 2; kk++) {
            const int co = (((kk << 2) + qd) ^ swr) << 3;
            bf16x8 af[4], bg[4];
#pragma unroll
            for (int t = 0; t < 4; t++) {
                af[t] = *(const bf16x8*)&As[(wm + t * 16 + ml) * 64 + co];
                bg[t] = *(const bf16x8*)&Bs[(wn + t * 16 + ml) * 64 + co];
            }
#pragma unroll
            for (int mt = 0; mt < 4; mt++)
#pragma unroll
                for (int nt = 0; nt < 4; nt++)
                    acc[mt][nt] = __builtin_amdgcn_mfma_f32_16x16x32_bf16(
                        af[mt], bg[nt], acc[mt][nt], 0, 0, 0);
        }
    }

    // rbf pass: one staged step over zero-padded operands (K 16..63 are 0);
    // only kk=0 contributes, kk=1 chunks are all-zero and skipped.
    __syncthreads();
#pragma unroll
    for (int j = 0; j < 4; j++) {
        const int i = wv * 4 + j;
        const int r = i * 8 + sr;
        gload_lds16(aR + (size_t)r * 64 + scs * 8, &As[i * 512]);
        gload_lds16(bR + (size_t)r * 64 + scs * 8, &Bs[i * 512]);
    }
    __syncthreads();
    {
        const int co = (qd ^ swr) << 3;
        bf16x8 af[4], bg[4];
#pragma unroll
        for (int t = 0; t < 4; t++) {
            af[t] = *(const bf16x8*)&As[(wm + t * 16 + ml) * 64 + co];
            bg[t] = *(const bf16x8*)&Bs[(wn + t * 16 + ml) * 64 + co];
        }
#pragma unroll
        for (int mt = 0; mt < 4; mt++)
#pragma unroll
            for (int nt = 0; nt < 4; nt++)
                accR[mt][nt] = __builtin_amdgcn_mfma_f32_16x16x32_bf16(
                    af[mt], bg[nt], accR[mt][nt], 0, 0, 0);
    }

    const float srbf = s_rbf[0];
#pragma unroll
    for (int mt = 0; mt < 4; mt++)
#pragma unroll
        for (int r = 0; r < 4; r++) {
            const int grow = row0 + wm + mt * 16 + qd * 4 + r;
            if (grow < NE) {
#pragma unroll
                for (int nt = 0; nt < 4; nt++) {
                    const int cc = col0 + wn + nt * 16 + ml;
                    float v = silu_f(acc[mt][nt][r]) * accR[mt][nt][r] * srbf;
                    x1[(size_t)grow * ED + cc] = (__bf16)v;
                }
            }
        }
}

// ---------------- k2: x2 = bf16( silu(x1 @ W_down) ) ------------------------
__global__ __launch_bounds__(256) void k2(const __bf16* __restrict__ x1,
                                          const float* __restrict__ Wdown,
                                          __bf16* __restrict__ x2)
{
    constexpr int BM = 128, BK = 64, LPA = 72, LPB = 72;  // 72 bf16 = 144 B rows
    __shared__ __bf16 As[BM * LPA];
    __shared__ __bf16 Bs[QI * LPB];

    const int tid = threadIdx.x;
    const int lane = tid & 63, wv = tid >> 6;
    const int ml = lane & 15, qd = lane >> 4;
    const int row0 = blockIdx.x * BM;
    const int wm = wv * 32;

    f32x4 acc[2][2];
    const f32x4 vz = {0.f, 0.f, 0.f, 0.f};
#pragma unroll
    for (int i = 0; i < 2; i++) { acc[i][0] = vz; acc[i][1] = vz; }

    for (int k0 = 0; k0 < ED; k0 += BK) {
        __syncthreads();
        // A: 128x64 bf16, already bf16 -> uint4 copies
#pragma unroll
        for (int f = tid; f < 1024; f += 256) {
            int r = f >> 3, c8 = (f & 7) * 8;
            uint4 v = make_uint4(0u, 0u, 0u, 0u);
            if (row0 + r < NE) v = *(const uint4*)(x1 + (size_t)(row0 + r) * ED + k0 + c8);
            *(uint4*)&As[r * LPA + c8] = v;
        }
        // B: Wdown[k0+kr][c] -> Bs[c][kr]
#pragma unroll
        for (int f = tid; f < BK * QI; f += 256) {
            int kr = f >> 5, c = f & 31;
            Bs[c * LPB + kr] = (__bf16)Wdown[(size_t)(k0 + kr) * QI + c];
        }
        __syncthreads();
#pragma unroll
        for (int kk = 0; kk < 2; kk++) {
            bf16x8 b0 = *(const bf16x8*)&Bs[(0  + ml) * LPB + kk * 32 + qd * 8];
            bf16x8 b1 = *(const bf16x8*)&Bs[(16 + ml) * LPB + kk * 32 + qd * 8];
#pragma unroll
            for (int mt = 0; mt < 2; mt++) {
                bf16x8 a = *(const bf16x8*)&As[(wm + mt * 16 + ml) * LPA + kk * 32 + qd * 8];
                acc[mt][0] = __builtin_amdgcn_mfma_f32_16x16x32_bf16(a, b0, acc[mt][0], 0, 0, 0);
                acc[mt][1] = __builtin_amdgcn_mfma_f32_16x16x32_bf16(a, b1, acc[mt][1], 0, 0, 0);
            }
        }
    }
#pragma unroll
    for (int mt = 0; mt < 2; mt++)
#pragma unroll
        for (int nt = 0; nt < 2; nt++)
#pragma unroll
            for (int r = 0; r < 4; r++) {
                int grow = row0 + wm + mt * 16 + qd * 4 + r;
                int cc = nt * 16 + ml;
                if (grow < NE) x2[(size_t)grow * QI + cc] = (__bf16)silu_f(acc[mt][nt][r]);
            }
}

// ---------------- k3: t[q] = x2[idx_trip_in[q]] * (cir@W_cbf)[q] * s_cbf ----
__global__ __launch_bounds__(256) void k3(const float* __restrict__ cir,
                                          const float* __restrict__ Wcbf,
                                          const float* __restrict__ s_cbf,
                                          const int* __restrict__ trip_in,
                                          const __bf16* __restrict__ x2,
                                          __bf16* __restrict__ t)
{
    constexpr int TPB = 64;
    __shared__ float cirs[TPB * CBF_];
    __shared__ float wc[CBF_ * QI];
    __shared__ int eix[TPB];

    const int tid = threadIdx.x;
    const int t0 = blockIdx.x * TPB;
#pragma unroll
    for (int i = tid; i < TPB * CBF_; i += 256) {
        int r = i >> 4, c = i & 15;
        cirs[i] = cir[(size_t)(t0 + r) * CBF_ + c];
    }
#pragma unroll
    for (int i = tid; i < CBF_ * QI; i += 256) wc[i] = Wcbf[i];
    if (tid < TPB) eix[tid] = trip_in[t0 + tid];
    __syncthreads();

    const float sc = s_cbf[0];
    const int d = tid & 31, ts0 = tid >> 5;
#pragma unroll
    for (int p = 0; p < TPB / 8; p++) {
        int ts = ts0 + p * 8;
        float a = 0.f;
#pragma unroll
        for (int c = 0; c < CBF_; c++) a += cirs[ts * CBF_ + c] * wc[c * QI + d];
        float xv = (float)x2[(size_t)eix[ts] * QI + d];
        t[(size_t)(t0 + ts) * QI + d] = (__bf16)(xv * a * sc);
    }
}

// ---------------- k4: per-edge bilinear (sum_k -> rW -> @W_bil) -> x --------
// Exploits idx_out=q/20, idx_out_agg=q%20: edge e owns quads e*20..e*20+19;
// m_pad slots k>=20 are zero and are skipped.
__global__ __launch_bounds__(256) void k4(const __bf16* __restrict__ t,
                                          const float* __restrict__ sph,
                                          const float* __restrict__ sphW1,
                                          const float* __restrict__ Wbil,
                                          const float* __restrict__ s_sbf,
                                          const int* __restrict__ t2q,
                                          float* __restrict__ x)
{
    constexpr int BE = 32;
    __shared__ float sumk[BE * NSPH_ * 32];      // 28672 B, f32 for accuracy
    __shared__ float sphs[BE * KAVG_ * NSPH_];   // 17920 B
    __shared__ int   qidx[BE * KAVG_];           //  2560 B
    __shared__ __bf16 rws[32 * 72];              //  4608 B (A chunk, M=32,K=64)
    __shared__ __bf16 wbs[32 * 72];              //  4608 B (B chunk transposed)

    const int tid = threadIdx.x;
    const int e0 = blockIdx.x * BE;
    const int d = tid & 31, eg = tid >> 5;
    const int lane = tid & 63, wv = tid >> 6;
    const int ml = lane & 15, qd = lane >> 4;
    const int mt = wv & 1, nt = wv >> 1;

    for (int i = tid; i < BE * KAVG_ * NSPH_; i += 256) {
        int e = i / (KAVG_ * NSPH_), rem = i % (KAVG_ * NSPH_);
        sphs[i] = sph[((size_t)(e0 + e) * 32) * NSPH_ + rem];  // rem = k*7+s, k<20
    }
    for (int i = tid; i < BE * KAVG_; i += 256) qidx[i] = t2q[(size_t)e0 * KAVG_ + i];
    __syncthreads();

    // phase 1: sum_k[e][s][d] = sum_k sph[e,k,s] * t[trip(e,k)][d]
    for (int e = eg; e < BE; e += 8) {
        float a[NSPH_] = {0.f, 0.f, 0.f, 0.f, 0.f, 0.f, 0.f};
        for (int k = 0; k < KAVG_; k++) {
            int q = qidx[e * KAVG_ + k];
            float tv = (float)t[(size_t)q * QI + d];
            const float* s7 = &sphs[(e * KAVG_ + k) * NSPH_];
#pragma unroll
            for (int s = 0; s < NSPH_; s++) a[s] += s7[s] * tv;
        }
#pragma unroll
        for (int s = 0; s < NSPH_; s++) sumk[(e * NSPH_ + s) * 32 + d] = a[s];
    }
    __syncthreads();

    // phase 2: K-chunked GEMM  x = (rW flat) @ W_bil, K=1024 in 16 chunks of 64
    f32x4 acc = {0.f, 0.f, 0.f, 0.f};
    for (int kc = 0; kc < 16; kc++) {
        __syncthreads();
#pragma unroll
        for (int j = 0; j < 4; j++) {
            int e = eg + 8 * j;
#pragma unroll
            for (int is = 0; is < 2; is++) {
                int i = kc * 2 + is;
                const float* w1 = &sphW1[((size_t)(e0 + e) * SBF_ + i) * NSPH_];
                float v = 0.f;
#pragma unroll
                for (int s = 0; s < NSPH_; s++) v += w1[s] * sumk[(e * NSPH_ + s) * 32 + d];
                rws[e * 72 + is * 32 + d] = (__bf16)v;
            }
        }
#pragma unroll
        for (int f = tid; f < 2048; f += 256) {
            int kr = f >> 5, o = f & 31;
            wbs[o * 72 + kr] = (__bf16)Wbil[(size_t)(kc * 64 + kr) * QO + o];
        }
        __syncthreads();
#pragma unroll
        for (int kk = 0; kk < 2; kk++) {
            bf16x8 a = *(const bf16x8*)&rws[(mt * 16 + ml) * 72 + kk * 32 + qd * 8];
            bf16x8 b = *(const bf16x8*)&wbs[(nt * 16 + ml) * 72 + kk * 32 + qd * 8];
            acc = __builtin_amdgcn_mfma_f32_16x16x32_bf16(a, b, acc, 0, 0, 0);
        }
    }
    const float ssb = s_sbf[0];
#pragma unroll
    for (int r = 0; r < 4; r++) {
        int e = mt * 16 + qd * 4 + r, o = nt * 16 + ml;
        x[(size_t)(e0 + e) * QO + o] = acc[r] * ssb;
    }
}

// ---------------- k5: out = (silu(x@Wca) + silu(x[swap]@Wac)) / sqrt(2) -----
__global__ __launch_bounds__(256) void k5(const float* __restrict__ x,
                                          const float* __restrict__ Wca,
                                          const float* __restrict__ Wac,
                                          const int* __restrict__ swp,
                                          float* __restrict__ outp)
{
    constexpr int BM = 128, BN = 128, LP = 40;  // K = 32 exactly one MFMA
    __shared__ __bf16 Aca[BM * LP];
    __shared__ __bf16 Aac[BM * LP];
    __shared__ __bf16 Bca[BN * LP];
    __shared__ __bf16 Bac[BN * LP];

    const int tid = threadIdx.x;
    const int lane = tid & 63, wv = tid >> 6;
    const int ml = lane & 15, qd = lane >> 4;
    const int row0 = blockIdx.x * BM, col0 = blockIdx.y * BN;
    const int wm = (wv >> 1) * 64, wn = (wv & 1) * 64;

#pragma unroll
    for (int f = tid; f < BM * 8; f += 256) {
        int r = f >> 3, c4 = (f & 7) * 4;
        int grow = row0 + r;
        float4 v = make_float4(0.f, 0.f, 0.f, 0.f);
        float4 w = make_float4(0.f, 0.f, 0.f, 0.f);
        if (grow < NE) {
            v = *(const float4*)(x + (size_t)grow * QI + c4);
            int sr = swp[grow];
            w = *(const float4*)(x + (size_t)sr * QI + c4);
        }
        __bf16* dv = &Aca[r * LP + c4];
        dv[0] = (__bf16)v.x; dv[1] = (__bf16)v.y; dv[2] = (__bf16)v.z; dv[3] = (__bf16)v.w;
        __bf16* dw = &Aac[r * LP + c4];
        dw[0] = (__bf16)w.x; dw[1] = (__bf16)w.y; dw[2] = (__bf16)w.z; dw[3] = (__bf16)w.w;
    }
#pragma unroll
    for (int f = tid; f < 1024; f += 256) {
        int kr = f >> 5, c4 = (f & 31) * 4;
        float4 v = *(const float4*)(Wca + (size_t)kr * ED + col0 + c4);
        float4 w = *(const float4*)(Wac + (size_t)kr * ED + col0 + c4);
        Bca[(c4 + 0) * LP + kr] = (__bf16)v.x;
        Bca[(c4 + 1) * LP + kr] = (__bf16)v.y;
        Bca[(c4 + 2) * LP + kr] = (__bf16)v.z;
        Bca[(c4 + 3) * LP + kr] = (__bf16)v.w;
        Bac[(c4 + 0) * LP + kr] = (__bf16)w.x;
        Bac[(c4 + 1) * LP + kr] = (__bf16)w.y;
        Bac[(c4 + 2) * LP + kr] = (__bf16)w.z;
        Bac[(c4 + 3) * LP + kr] = (__bf16)w.w;
    }
    __syncthreads();

    f32x4 aC[4][4], aA[4][4];
    const f32x4 vz = {0.f, 0.f, 0.f, 0.f};
#pragma unroll
    for (int i = 0; i < 4; i++)
#pragma unroll
        for (int j = 0; j < 4; j++) { aC[i][j] = vz; aA[i][j] = vz; }

    bf16x8 afC[4], afA[4], bfC[4], bfA[4];
#pragma unroll
    for (int i = 0; i < 4; i++) {
        afC[i] = *(const bf16x8*)&Aca[(wm + i * 16 + ml) * LP + qd * 8];
        afA[i] = *(const bf16x8*)&Aac[(wm + i * 16 + ml) * LP + qd * 8];
        bfC[i] = *(const bf16x8*)&Bca[(wn + i * 16 + ml) * LP + qd * 8];
        bfA[i] = *(const bf16x8*)&Bac[(wn + i * 16 + ml) * LP + qd * 8];
    }
#pragma unroll
    for (int mt = 0; mt < 4; mt++)
#pragma unroll
        for (int nt = 0; nt < 4; nt++) {
            aC[mt][nt] = __builtin_amdgcn_mfma_f32_16x16x32_bf16(afC[mt], bfC[nt], aC[mt][nt], 0, 0, 0);
            aA[mt][nt] = __builtin_amdgcn_mfma_f32_16x16x32_bf16(afA[mt], bfA[nt], aA[mt][nt], 0, 0, 0);
        }

    const float inv_sqrt2 = 0.70710678118654752440f;
#pragma unroll
    for (int mt = 0; mt < 4; mt++)
#pragma unroll
        for (int r = 0; r < 4; r++) {
            int grow = row0 + wm + mt * 16 + qd * 4 + r;
            if (grow < NE) {
#pragma unroll
                for (int nt = 0; nt < 4; nt++) {
                    int cc = wn + nt * 16 + ml;
                    float v = (silu_f(aC[mt][nt][r]) + silu_f(aA[mt][nt][r])) * inv_sqrt2;
                    outp[(size_t)grow * ED + col0 + cc] = v;
                }
            }
        }
}

// ---------------------------------------------------------------------------
extern "C" void kernel_launch(void* const* d_in, const int* in_sizes, int n_in,
                              void* d_out, int out_size, void* d_ws, size_t ws_size,
                              hipStream_t stream)
{
    (void)in_sizes; (void)n_in; (void)out_size; (void)ws_size;

    const float* mM    = (const float*)d_in[0];
    const float* rad   = (const float*)d_in[1];
    const float* cir   = (const float*)d_in[2];
    const float* sphW1 = (const float*)d_in[3];
    const float* sph   = (const float*)d_in[4];
    const float* Wdb   = (const float*)d_in[5];
    const float* Wrbf  = (const float*)d_in[6];
    const float* Wdown = (const float*)d_in[7];
    const float* Wcbf  = (const float*)d_in[8];
    const float* Wbil  = (const float*)d_in[9];
    const float* Wca   = (const float*)d_in[10];
    const float* Wac   = (const float*)d_in[11];
    const float* s_rbf = (const float*)d_in[12];
    const float* s_cbf = (const float*)d_in[13];
    const float* s_sbf = (const float*)d_in[14];
    const int* trip_in = (const int*)d_in[15];
    const int* t2q     = (const int*)d_in[16];
    const int* swp     = (const int*)d_in[19];

    char* ws = (char*)d_ws;
    __bf16* x1 = (__bf16*)(ws);                  // NE*512 bf16 = 102,400,000 B
    __bf16* x2 = (__bf16*)(ws + 102400000);      // NE*32  bf16 =   6,400,000 B
    __bf16* tt = (__bf16*)(ws + 108800000);      // NT*32  bf16 =  64,000,000 B
    float*  xx = (float*) (ws + 172800000);      // NE*32  f32  =  12,800,000 B

    // k0/k1-lifetime scratch:
    //   mB in d_out (204.8 MB; k5 overwrites it as the final step)
    //   WdbT/radp/WrbfT in the tt region (k3 overwrites only AFTER k1 is done)
    __bf16* mB    = (__bf16*)d_out;                                 // 102,498,304 B
    __bf16* WdbT  = (__bf16*)(ws + 108800000);                      //     524,288 B
    __bf16* radp  = (__bf16*)(ws + 108800000 + 524288);             //  12,812,288 B
    __bf16* WrbfT = (__bf16*)(ws + 108800000 + 524288 + 12812288);  //      65,536 B

    constexpr int GM = (NE + 127) / 128;  // 782

    k0<<<2080, 256, 0, stream>>>(mM, Wdb, rad, Wrbf, mB, WdbT, radp, WrbfT);
    k1<<<dim3(4, GM), 256, 0, stream>>>(mB, WdbT, radp, WrbfT, s_rbf, x1);
    k2<<<GM, 256, 0, stream>>>(x1, Wdown, x2);
    k3<<<NT / 64, 256, 0, stream>>>(cir, Wcbf, s_cbf, trip_in, x2, tt);
    k4<<<NE / 32, 256, 0, stream>>>(tt, sph, sphW1, Wbil, s_sbf, t2q, xx);
    k5<<<dim3(GM, 4), 256, 0, stream>>>(xx, Wca, Wac, swp, (float*)d_out);
}

// Round 2
// 941.376 us; speedup vs baseline: 1.3919x; 1.1137x over previous
//
#include <hip/hip_runtime.h>
#include <hip/hip_bf16.h>

// ---------------------------------------------------------------------------
// QuadrupletInteraction (GemNet-style), MI355X / gfx950.
// Pipeline: k0 (bf16 prep: m, Wdb^T, rad-pad, Wrbf^T, Wbil^T) -> k1 (m@W_db
// fused rbf, global_load_lds + XOR-swizzle MFMA GEMM) -> k2 (down-proj) ->
// k3 (cbf mul + edge->trip gather) -> k4a (ragged gather -> sumk) ->
// k4b (per-edge bilinear -> x) -> k5 (up-projections + swap).
// Scratch plan:
//   d_out (204.8 MB): mB [100096][512] bf16 @0 (k0..k1) | WbilT @103,000,000
//                     (k0..k4b); k5 overwrites d_out last.
//   ws x1-region: x1 bf16 (k1..k2), then sumk f32 [NE][7][32] (k4a..k4b).
//   ws tt-region head: WdbT | radp | WrbfT (k0..k1); k3 overwrites after.
// Error budget: bf16-rounded GEMM inputs, f32 accumulation everywhere.
// k4a/k4b math is bit-identical to the previous fused k4.
// ---------------------------------------------------------------------------

constexpr int NE   = 100000;   // edges
constexpr int NEP  = 100096;   // 782*128, row-padded (guard-free staging)
constexpr int ED   = 512;      // E
constexpr int NT   = 1000000;  // triplets
constexpr int NQ   = 2000000;  // quadruplets
constexpr int QI   = 32;       // QIN
constexpr int QO   = 32;       // QOUT
constexpr int RBF_ = 16;
constexpr int CBF_ = 16;
constexpr int SBF_ = 32;
constexpr int NSPH_= 7;
constexpr int KAVG_= 20;

typedef float f32x4 __attribute__((ext_vector_type(4)));
typedef __bf16 bf16x8 __attribute__((ext_vector_type(8)));
typedef __bf16 bf16x4 __attribute__((ext_vector_type(4)));

__device__ __forceinline__ float silu_f(float v) {
    return __fdividef(v, 1.0f + __expf(-v));
}

// async global->LDS, 16B per lane; LDS dest is wave-uniform base + lane*16
__device__ __forceinline__ void gload_lds16(const __bf16* g, __bf16* l) {
    __builtin_amdgcn_global_load_lds(
        (const __attribute__((address_space(1))) void*)g,
        (__attribute__((address_space(3))) void*)l, 16, 0, 0);
}

// ---------------- k0: bf16 prep ---------------------------------------------
// blocks [0,1600)    : mB[NEP][512] = bf16(m), pad rows zeroed
// blocks [1600,1664) : WdbT[512][512] = bf16(Wdb^T)   (64x64 LDS tiles)
// blocks [1664,2064) : radp[NEP][64]  = bf16(rad) cols<16, else 0; pad rows 0
// blocks [2064,2080) : WrbfT[512][64] = bf16(Wrbf^T) rows k<16, else 0
// blocks [2080,2088) : WbilT[32][1024] = bf16(Wbil^T)
__global__ __launch_bounds__(256) void k0(const float* __restrict__ mM,
                                          const float* __restrict__ Wdb,
                                          const float* __restrict__ rad,
                                          const float* __restrict__ Wrbf,
                                          const float* __restrict__ Wbil,
                                          __bf16* __restrict__ mB,
                                          __bf16* __restrict__ WdbT,
                                          __bf16* __restrict__ radp,
                                          __bf16* __restrict__ WrbfT,
                                          __bf16* __restrict__ WbilT)
{
    const int b = blockIdx.x, tid = threadIdx.x;
    if (b < 1600) {
        const long total = (long)NEP * ED / 8;   // 6,406,144 chunks of 8
        for (long g = (long)b * 256 + tid; g < total; g += 409600L) {
            const long e0 = g * 8;
            const int row = (int)(e0 >> 9);
            bf16x8 o;
            if (row < NE) {
                const float4 v0 = *(const float4*)(mM + e0);
                const float4 v1 = *(const float4*)(mM + e0 + 4);
                o[0] = (__bf16)v0.x; o[1] = (__bf16)v0.y;
                o[2] = (__bf16)v0.z; o[3] = (__bf16)v0.w;
                o[4] = (__bf16)v1.x; o[5] = (__bf16)v1.y;
                o[6] = (__bf16)v1.z; o[7] = (__bf16)v1.w;
            } else {
#pragma unroll
                for (int j = 0; j < 8; j++) o[j] = (__bf16)0.f;
            }
            *(bf16x8*)(mB + e0) = o;
        }
    } else if (b < 1664) {
        __shared__ float tle[64 * 65];
        const int idx = b - 1600;
        const int kb = (idx >> 3) * 64, nb = (idx & 7) * 64;
#pragma unroll
        for (int f = tid; f < 1024; f += 256) {
            const int kk = f >> 4, n4 = (f & 15) * 4;
            const float4 v = *(const float4*)(Wdb + (size_t)(kb + kk) * ED + nb + n4);
            tle[(n4 + 0) * 65 + kk] = v.x;
            tle[(n4 + 1) * 65 + kk] = v.y;
            tle[(n4 + 2) * 65 + kk] = v.z;
            tle[(n4 + 3) * 65 + kk] = v.w;
        }
        __syncthreads();
#pragma unroll
        for (int f = tid; f < 1024; f += 256) {
            const int nn = f >> 4, k4 = (f & 15) * 4;
            bf16x4 o;
            o[0] = (__bf16)tle[nn * 65 + k4 + 0];
            o[1] = (__bf16)tle[nn * 65 + k4 + 1];
            o[2] = (__bf16)tle[nn * 65 + k4 + 2];
            o[3] = (__bf16)tle[nn * 65 + k4 + 3];
            *(bf16x4*)(WdbT + (size_t)(nb + nn) * ED + kb + k4) = o;
        }
    } else if (b < 2064) {
        for (int g = (b - 1664) * 256 + tid; g < NEP * 8; g += 102400) {
            const int row = g >> 3, c = g & 7;
            bf16x8 o;
            if (row < NE && c < 2) {
                const float* s = rad + (size_t)row * RBF_ + c * 8;
                const float4 v0 = *(const float4*)s;
                const float4 v1 = *(const float4*)(s + 4);
                o[0] = (__bf16)v0.x; o[1] = (__bf16)v0.y;
                o[2] = (__bf16)v0.z; o[3] = (__bf16)v0.w;
                o[4] = (__bf16)v1.x; o[5] = (__bf16)v1.y;
                o[6] = (__bf16)v1.z; o[7] = (__bf16)v1.w;
            } else {
#pragma unroll
                for (int j = 0; j < 8; j++) o[j] = (__bf16)0.f;
            }
            *(bf16x8*)(radp + (size_t)row * 64 + c * 8) = o;
        }
    } else if (b < 2080) {
        for (int f = (b - 2064) * 256 + tid; f < 512 * 64; f += 4096) {
            const int n = f >> 6, k = f & 63;
            const float v = (k < RBF_) ? Wrbf[(size_t)k * ED + n] : 0.f;
            WrbfT[(size_t)n * 64 + k] = (__bf16)v;
        }
    } else {
        // WbilT[o][k] = bf16(Wbil[k][o]); 32x1024, tiny (128 KB read)
        for (int f = (b - 2080) * 256 + tid; f < 32 * 1024; f += 2048) {
            const int o = f >> 10, k = f & 1023;
            WbilT[(size_t)o * 1024 + k] = (__bf16)Wbil[(size_t)k * QO + o];
        }
    }
}

// ---------------- k1: x1 = bf16( silu(m@W_db) * (rad@W_rbf) * s_rbf ) -------
// m97-structure GEMM: 128x128 tile, BK=64, global_load_lds width-16 staging.
// LDS tiles As/Bs: row-major [128][64] bf16 (128 B rows), 16-B chunk XOR-
// swizzled by (row&7). Swizzle applied on BOTH sides (rule #21): linear LDS
// dest + inverse-swizzled global source in staging, same XOR on ds_read.
__global__ __launch_bounds__(256) void k1(const __bf16* __restrict__ mB,
                                          const __bf16* __restrict__ WdbT,
                                          const __bf16* __restrict__ radp,
                                          const __bf16* __restrict__ WrbfT,
                                          const float* __restrict__ s_rbf,
                                          __bf16* __restrict__ x1)
{
    __shared__ __align__(16) __bf16 As[128 * 64];
    __shared__ __align__(16) __bf16 Bs[128 * 64];

    const int tid  = threadIdx.x;
    const int lane = tid & 63, wv = tid >> 6;
    const int ml = lane & 15, qd = lane >> 4;
    const int col0 = blockIdx.x * 128;   // 4 col-blocks (adjacent dispatch -> A reuse in L2)
    const int row0 = blockIdx.y * 128;   // 782 row-blocks
    const int wm = (wv >> 1) * 64, wn = (wv & 1) * 64;

    const int sr  = lane >> 3;
    const int scs = (lane & 7) ^ sr;     // pre-swizzled source chunk
    const int swr = ml & 7;              // read-side XOR (row&7 == ml&7)

    f32x4 acc[4][4], accR[4][4];
    const f32x4 vz = {0.f, 0.f, 0.f, 0.f};
#pragma unroll
    for (int i = 0; i < 4; i++)
#pragma unroll
        for (int j = 0; j < 4; j++) { acc[i][j] = vz; accR[i][j] = vz; }

    const __bf16* aT = mB    + (size_t)row0 * ED;
    const __bf16* bT = WdbT  + (size_t)col0 * ED;
    const __bf16* aR = radp  + (size_t)row0 * 64;
    const __bf16* bR = WrbfT + (size_t)col0 * 64;

    for (int k0 = 0; k0 < ED; k0 += 64) {
        __syncthreads();
#pragma unroll
        for (int j = 0; j < 4; j++) {
            const int i = wv * 4 + j;
            const int r = i * 8 + sr;
            gload_lds16(aT + (size_t)r * ED + k0 + scs * 8, &As[i * 512]);
            gload_lds16(bT + (size_t)r * ED + k0 + scs * 8, &Bs[i * 512]);
        }
        __syncthreads();
#pragma unroll
        for (int kk = 0; kk < 2; kk++) {
            const int co = (((kk << 2) + qd) ^ swr) << 3;
            bf16x8 af[4], bg[4];
#pragma unroll
            for (int t = 0; t < 4; t++) {
                af[t] = *(const bf16x8*)&As[(wm + t * 16 + ml) * 64 + co];
                bg[t] = *(const bf16x8*)&Bs[(wn + t * 16 + ml) * 64 + co];
            }
#pragma unroll
            for (int mt = 0; mt < 4; mt++)
#pragma unroll
                for (int nt = 0; nt < 4; nt++)
                    acc[mt][nt] = __builtin_amdgcn_mfma_f32_16x16x32_bf16(
                        af[mt], bg[nt], acc[mt][nt], 0, 0, 0);
        }
    }

    // rbf pass: one staged step over zero-padded operands (K 16..63 are 0)
    __syncthreads();
#pragma unroll
    for (int j = 0; j < 4; j++) {
        const int i = wv * 4 + j;
        const int r = i * 8 + sr;
        gload_lds16(aR + (size_t)r * 64 + scs * 8, &As[i * 512]);
        gload_lds16(bR + (size_t)r * 64 + scs * 8, &Bs[i * 512]);
    }
    __syncthreads();
    {
        const int co = (qd ^ swr) << 3;
        bf16x8 af[4], bg[4];
#pragma unroll
        for (int t = 0; t < 4; t++) {
            af[t] = *(const bf16x8*)&As[(wm + t * 16 + ml) * 64 + co];
            bg[t] = *(const bf16x8*)&Bs[(wn + t * 16 + ml) * 64 + co];
        }
#pragma unroll
        for (int mt = 0; mt < 4; mt++)
#pragma unroll
            for (int nt = 0; nt < 4; nt++)
                accR[mt][nt] = __builtin_amdgcn_mfma_f32_16x16x32_bf16(
                    af[mt], bg[nt], accR[mt][nt], 0, 0, 0);
    }

    const float srbf = s_rbf[0];
#pragma unroll
    for (int mt = 0; mt < 4; mt++)
#pragma unroll
        for (int r = 0; r < 4; r++) {
            const int grow = row0 + wm + mt * 16 + qd * 4 + r;
            if (grow < NE) {
#pragma unroll
                for (int nt = 0; nt < 4; nt++) {
                    const int cc = col0 + wn + nt * 16 + ml;
                    float v = silu_f(acc[mt][nt][r]) * accR[mt][nt][r] * srbf;
                    x1[(size_t)grow * ED + cc] = (__bf16)v;
                }
            }
        }
}

// ---------------- k2: x2 = bf16( silu(x1 @ W_down) ) ------------------------
__global__ __launch_bounds__(256) void k2(const __bf16* __restrict__ x1,
                                          const float* __restrict__ Wdown,
                                          __bf16* __restrict__ x2)
{
    constexpr int BM = 128, BK = 64, LPA = 72, LPB = 72;  // 72 bf16 = 144 B rows
    __shared__ __bf16 As[BM * LPA];
    __shared__ __bf16 Bs[QI * LPB];

    const int tid = threadIdx.x;
    const int lane = tid & 63, wv = tid >> 6;
    const int ml = lane & 15, qd = lane >> 4;
    const int row0 = blockIdx.x * BM;
    const int wm = wv * 32;

    f32x4 acc[2][2];
    const f32x4 vz = {0.f, 0.f, 0.f, 0.f};
#pragma unroll
    for (int i = 0; i < 2; i++) { acc[i][0] = vz; acc[i][1] = vz; }

    for (int k0 = 0; k0 < ED; k0 += BK) {
        __syncthreads();
#pragma unroll
        for (int f = tid; f < 1024; f += 256) {
            int r = f >> 3, c8 = (f & 7) * 8;
            uint4 v = make_uint4(0u, 0u, 0u, 0u);
            if (row0 + r < NE) v = *(const uint4*)(x1 + (size_t)(row0 + r) * ED + k0 + c8);
            *(uint4*)&As[r * LPA + c8] = v;
        }
#pragma unroll
        for (int f = tid; f < BK * QI; f += 256) {
            int kr = f >> 5, c = f & 31;
            Bs[c * LPB + kr] = (__bf16)Wdown[(size_t)(k0 + kr) * QI + c];
        }
        __syncthreads();
#pragma unroll
        for (int kk = 0; kk < 2; kk++) {
            bf16x8 b0 = *(const bf16x8*)&Bs[(0  + ml) * LPB + kk * 32 + qd * 8];
            bf16x8 b1 = *(const bf16x8*)&Bs[(16 + ml) * LPB + kk * 32 + qd * 8];
#pragma unroll
            for (int mt = 0; mt < 2; mt++) {
                bf16x8 a = *(const bf16x8*)&As[(wm + mt * 16 + ml) * LPA + kk * 32 + qd * 8];
                acc[mt][0] = __builtin_amdgcn_mfma_f32_16x16x32_bf16(a, b0, acc[mt][0], 0, 0, 0);
                acc[mt][1] = __builtin_amdgcn_mfma_f32_16x16x32_bf16(a, b1, acc[mt][1], 0, 0, 0);
            }
        }
    }
#pragma unroll
    for (int mt = 0; mt < 2; mt++)
#pragma unroll
        for (int nt = 0; nt < 2; nt++)
#pragma unroll
            for (int r = 0; r < 4; r++) {
                int grow = row0 + wm + mt * 16 + qd * 4 + r;
                int cc = nt * 16 + ml;
                if (grow < NE) x2[(size_t)grow * QI + cc] = (__bf16)silu_f(acc[mt][nt][r]);
            }
}

// ---------------- k3: t[q] = x2[idx_trip_in[q]] * (cir@W_cbf)[q] * s_cbf ----
__global__ __launch_bounds__(256) void k3(const float* __restrict__ cir,
                                          const float* __restrict__ Wcbf,
                                          const float* __restrict__ s_cbf,
                                          const int* __restrict__ trip_in,
                                          const __bf16* __restrict__ x2,
                                          __bf16* __restrict__ t)
{
    constexpr int TPB = 64;
    __shared__ float cirs[TPB * CBF_];
    __shared__ float wc[CBF_ * QI];
    __shared__ int eix[TPB];

    const int tid = threadIdx.x;
    const int t0 = blockIdx.x * TPB;
#pragma unroll
    for (int i = tid; i < TPB * CBF_; i += 256) {
        int r = i >> 4, c = i & 15;
        cirs[i] = cir[(size_t)(t0 + r) * CBF_ + c];
    }
#pragma unroll
    for (int i = tid; i < CBF_ * QI; i += 256) wc[i] = Wcbf[i];
    if (tid < TPB) eix[tid] = trip_in[t0 + tid];
    __syncthreads();

    const float sc = s_cbf[0];
    const int d = tid & 31, ts0 = tid >> 5;
#pragma unroll
    for (int p = 0; p < TPB / 8; p++) {
        int ts = ts0 + p * 8;
        float a = 0.f;
#pragma unroll
        for (int c = 0; c < CBF_; c++) a += cirs[ts * CBF_ + c] * wc[c * QI + d];
        float xv = (float)x2[(size_t)eix[ts] * QI + d];
        t[(size_t)(t0 + ts) * QI + d] = (__bf16)(xv * a * sc);
    }
}

// ---------------- k4a: sumk[e][s][d] = sum_{k<20} sph[e,k,s]*t[t2q[e,k]][d] -
// 256 thr = 32 groups x 8 lanes; group owns one edge; lane owns a d-quad.
// Each lane: 20 independent 8-B gathers of t (fully unrolled) -> f32 accum.
// LDS exactly 20,480 B; high occupancy hides the random-gather latency.
__global__ __launch_bounds__(256, 4) void k4a(const __bf16* __restrict__ t,
                                              const float* __restrict__ sph,
                                              const int* __restrict__ t2q,
                                              float* __restrict__ sumk)
{
    __shared__ float sphs[32 * KAVG_ * NSPH_];   // 17920 B
    __shared__ int   qidx[32 * KAVG_];           //  2560 B

    const int tid = threadIdx.x;
    const int e0 = blockIdx.x * 32;

    for (int i = tid; i < 32 * KAVG_ * NSPH_; i += 256) {
        int e = i / (KAVG_ * NSPH_), rem = i % (KAVG_ * NSPH_);
        sphs[i] = sph[((size_t)(e0 + e) * 32) * NSPH_ + rem];  // rem = k*7+s, k<20
    }
    for (int i = tid; i < 32 * KAVG_; i += 256) qidx[i] = t2q[(size_t)e0 * KAVG_ + i];
    __syncthreads();

    const int g = tid >> 3;            // edge group 0..31
    const int dq = (tid & 7) * 4;      // d-quad base

    f32x4 a[NSPH_];
#pragma unroll
    for (int s = 0; s < NSPH_; s++) a[s] = (f32x4){0.f, 0.f, 0.f, 0.f};

#pragma unroll
    for (int k = 0; k < KAVG_; k++) {
        const int q = qidx[g * KAVG_ + k];
        const bf16x4 tv = *(const bf16x4*)(t + (size_t)q * QI + dq);
        f32x4 tf;
#pragma unroll
        for (int j = 0; j < 4; j++) tf[j] = (float)tv[j];
        const float* s7 = &sphs[(g * KAVG_ + k) * NSPH_];
#pragma unroll
        for (int s = 0; s < NSPH_; s++) {
            const float w = s7[s];
#pragma unroll
            for (int j = 0; j < 4; j++) a[s][j] += w * tf[j];
        }
    }
#pragma unroll
    for (int s = 0; s < NSPH_; s++)
        *(f32x4*)(sumk + ((size_t)(e0 + g) * NSPH_ + s) * 32 + dq) = a[s];
}

// ---------------- k4b: per-edge bilinear (rW -> @W_bil) -> x ----------------
// Stages sumk AND sphW1 into LDS once (coalesced); each thread preloads its
// 28 sumk values to registers. Per-kc: LDS-broadcast FMAs + one uint4 load of
// pre-transposed WbilT + 2 MFMAs. No scalar global loads in the hot loop.
__global__ __launch_bounds__(256) void k4b(const float* __restrict__ sumk,
                                           const float* __restrict__ sphW1,
                                           const __bf16* __restrict__ WbilT,
                                           const float* __restrict__ s_sbf,
                                           float* __restrict__ x)
{
    __shared__ float sks[32 * NSPH_ * 32];   // 28672 B
    __shared__ float w1s[32 * SBF_ * NSPH_]; // 28672 B
    __shared__ __bf16 rws[32 * 72];          //  4608 B (A chunk, M=32,K=64)
    __shared__ __bf16 wbs[32 * 72];          //  4608 B (B chunk, o-major)

    const int tid = threadIdx.x;
    const int e0 = blockIdx.x * 32;

    // stage sumk + sphW1: 1792 float4 each, fully coalesced
    for (int i = tid; i < 1792; i += 256) {
        *(float4*)&sks[i * 4] = *(const float4*)(sumk  + (size_t)e0 * 224 + i * 4);
        *(float4*)&w1s[i * 4] = *(const float4*)(sphW1 + (size_t)e0 * 224 + i * 4);
    }
    __syncthreads();

    const int d = tid & 31, eg = tid >> 5;
    const int lane = tid & 63, wv = tid >> 6;
    const int ml = lane & 15, qd = lane >> 4;
    const int mt = wv & 1, nt = wv >> 1;

    // preload this thread's sumk slice: 4 edges x 7 s
    float sk[4][NSPH_];
#pragma unroll
    for (int j = 0; j < 4; j++)
#pragma unroll
        for (int s = 0; s < NSPH_; s++)
            sk[j][s] = sks[((eg + 8 * j) * NSPH_ + s) * 32 + d];

    const int wo = tid >> 3, wc8 = (tid & 7) * 8;  // wbs staging coords

    f32x4 acc = {0.f, 0.f, 0.f, 0.f};
    for (int kc = 0; kc < 16; kc++) {
        __syncthreads();
        // rws for i = kc*2, kc*2+1 (w1 broadcasts from LDS, sk from regs)
#pragma unroll
        for (int j = 0; j < 4; j++) {
            const int e = eg + 8 * j;
#pragma unroll
            for (int is = 0; is < 2; is++) {
                const int i = kc * 2 + is;
                const float* w1 = &w1s[(e * SBF_ + i) * NSPH_];
                float v = 0.f;
#pragma unroll
                for (int s = 0; s < NSPH_; s++) v += w1[s] * sk[j][s];
                rws[e * 72 + is * 32 + d] = (__bf16)v;
            }
        }
        // wbs[o][0..63] <- WbilT[o][kc*64..], one uint4 per thread
        *(bf16x8*)&wbs[wo * 72 + wc8] =
            *(const bf16x8*)(WbilT + (size_t)wo * 1024 + kc * 64 + wc8);
        __syncthreads();
#pragma unroll
        for (int kk = 0; kk < 2; kk++) {
            bf16x8 a = *(const bf16x8*)&rws[(mt * 16 + ml) * 72 + kk * 32 + qd * 8];
            bf16x8 b = *(const bf16x8*)&wbs[(nt * 16 + ml) * 72 + kk * 32 + qd * 8];
            acc = __builtin_amdgcn_mfma_f32_16x16x32_bf16(a, b, acc, 0, 0, 0);
        }
    }
    const float ssb = s_sbf[0];
#pragma unroll
    for (int r = 0; r < 4; r++) {
        int e = mt * 16 + qd * 4 + r, o = nt * 16 + ml;
        x[(size_t)(e0 + e) * QO + o] = acc[r] * ssb;
    }
}

// ---------------- k5: out = (silu(x@Wca) + silu(x[swap]@Wac)) / sqrt(2) -----
__global__ __launch_bounds__(256) void k5(const float* __restrict__ x,
                                          const float* __restrict__ Wca,
                                          const float* __restrict__ Wac,
                                          const int* __restrict__ swp,
                                          float* __restrict__ outp)
{
    constexpr int BM = 128, BN = 128, LP = 40;  // K = 32 exactly one MFMA
    __shared__ __bf16 Aca[BM * LP];
    __shared__ __bf16 Aac[BM * LP];
    __shared__ __bf16 Bca[BN * LP];
    __shared__ __bf16 Bac[BN * LP];

    const int tid = threadIdx.x;
    const int lane = tid & 63, wv = tid >> 6;
    const int ml = lane & 15, qd = lane >> 4;
    const int row0 = blockIdx.x * BM, col0 = blockIdx.y * BN;
    const int wm = (wv >> 1) * 64, wn = (wv & 1) * 64;

#pragma unroll
    for (int f = tid; f < BM * 8; f += 256) {
        int r = f >> 3, c4 = (f & 7) * 4;
        int grow = row0 + r;
        float4 v = make_float4(0.f, 0.f, 0.f, 0.f);
        float4 w = make_float4(0.f, 0.f, 0.f, 0.f);
        if (grow < NE) {
            v = *(const float4*)(x + (size_t)grow * QI + c4);
            int sr = swp[grow];
            w = *(const float4*)(x + (size_t)sr * QI + c4);
        }
        __bf16* dv = &Aca[r * LP + c4];
        dv[0] = (__bf16)v.x; dv[1] = (__bf16)v.y; dv[2] = (__bf16)v.z; dv[3] = (__bf16)v.w;
        __bf16* dw = &Aac[r * LP + c4];
        dw[0] = (__bf16)w.x; dw[1] = (__bf16)w.y; dw[2] = (__bf16)w.z; dw[3] = (__bf16)w.w;
    }
#pragma unroll
    for (int f = tid; f < 1024; f += 256) {
        int kr = f >> 5, c4 = (f & 31) * 4;
        float4 v = *(const float4*)(Wca + (size_t)kr * ED + col0 + c4);
        float4 w = *(const float4*)(Wac + (size_t)kr * ED + col0 + c4);
        Bca[(c4 + 0) * LP + kr] = (__bf16)v.x;
        Bca[(c4 + 1) * LP + kr] = (__bf16)v.y;
        Bca[(c4 + 2) * LP + kr] = (__bf16)v.z;
        Bca[(c4 + 3) * LP + kr] = (__bf16)v.w;
        Bac[(c4 + 0) * LP + kr] = (__bf16)w.x;
        Bac[(c4 + 1) * LP + kr] = (__bf16)w.y;
        Bac[(c4 + 2) * LP + kr] = (__bf16)w.z;
        Bac[(c4 + 3) * LP + kr] = (__bf16)w.w;
    }
    __syncthreads();

    f32x4 aC[4][4], aA[4][4];
    const f32x4 vz = {0.f, 0.f, 0.f, 0.f};
#pragma unroll
    for (int i = 0; i < 4; i++)
#pragma unroll
        for (int j = 0; j < 4; j++) { aC[i][j] = vz; aA[i][j] = vz; }

    bf16x8 afC[4], afA[4], bfC[4], bfA[4];
#pragma unroll
    for (int i = 0; i < 4; i++) {
        afC[i] = *(const bf16x8*)&Aca[(wm + i * 16 + ml) * LP + qd * 8];
        afA[i] = *(const bf16x8*)&Aac[(wm + i * 16 + ml) * LP + qd * 8];
        bfC[i] = *(const bf16x8*)&Bca[(wn + i * 16 + ml) * LP + qd * 8];
        bfA[i] = *(const bf16x8*)&Bac[(wn + i * 16 + ml) * LP + qd * 8];
    }
#pragma unroll
    for (int mt = 0; mt < 4; mt++)
#pragma unroll
        for (int nt = 0; nt < 4; nt++) {
            aC[mt][nt] = __builtin_amdgcn_mfma_f32_16x16x32_bf16(afC[mt], bfC[nt], aC[mt][nt], 0, 0, 0);
            aA[mt][nt] = __builtin_amdgcn_mfma_f32_16x16x32_bf16(afA[mt], bfA[nt], aA[mt][nt], 0, 0, 0);
        }

    const float inv_sqrt2 = 0.70710678118654752440f;
#pragma unroll
    for (int mt = 0; mt < 4; mt++)
#pragma unroll
        for (int r = 0; r < 4; r++) {
            int grow = row0 + wm + mt * 16 + qd * 4 + r;
            if (grow < NE) {
#pragma unroll
                for (int nt = 0; nt < 4; nt++) {
                    int cc = wn + nt * 16 + ml;
                    float v = (silu_f(aC[mt][nt][r]) + silu_f(aA[mt][nt][r])) * inv_sqrt2;
                    outp[(size_t)grow * ED + col0 + cc] = v;
                }
            }
        }
}

// ---------------------------------------------------------------------------
extern "C" void kernel_launch(void* const* d_in, const int* in_sizes, int n_in,
                              void* d_out, int out_size, void* d_ws, size_t ws_size,
                              hipStream_t stream)
{
    (void)in_sizes; (void)n_in; (void)out_size; (void)ws_size;

    const float* mM    = (const float*)d_in[0];
    const float* rad   = (const float*)d_in[1];
    const float* cir   = (const float*)d_in[2];
    const float* sphW1 = (const float*)d_in[3];
    const float* sph   = (const float*)d_in[4];
    const float* Wdb   = (const float*)d_in[5];
    const float* Wrbf  = (const float*)d_in[6];
    const float* Wdown = (const float*)d_in[7];
    const float* Wcbf  = (const float*)d_in[8];
    const float* Wbil  = (const float*)d_in[9];
    const float* Wca   = (const float*)d_in[10];
    const float* Wac   = (const float*)d_in[11];
    const float* s_rbf = (const float*)d_in[12];
    const float* s_cbf = (const float*)d_in[13];
    const float* s_sbf = (const float*)d_in[14];
    const int* trip_in = (const int*)d_in[15];
    const int* t2q     = (const int*)d_in[16];
    const int* swp     = (const int*)d_in[19];

    char* ws = (char*)d_ws;
    __bf16* x1 = (__bf16*)(ws);                  // NE*512 bf16 = 102,400,000 B (k1..k2)
    __bf16* x2 = (__bf16*)(ws + 102400000);      // NE*32  bf16 =   6,400,000 B
    __bf16* tt = (__bf16*)(ws + 108800000);      // NT*32  bf16 =  64,000,000 B
    float*  xx = (float*) (ws + 172800000);      // NE*32  f32  =  12,800,000 B
    float*  smk= (float*) (ws);                  // NE*224 f32  =  89,600,000 B (k4a..k4b, x1 dead)

    // k0/k1-lifetime scratch:
    //   mB in d_out [0, 102.5 MB); WbilT in d_out @103,000,000 (k4b reads it;
    //   both overwritten only by k5 at the very end)
    //   WdbT/radp/WrbfT in the tt region (k3 overwrites only AFTER k1 is done)
    __bf16* mB    = (__bf16*)d_out;                                 // 102,498,304 B
    __bf16* WbilT = (__bf16*)((char*)d_out + 103000000);            //      65,536 B
    __bf16* WdbT  = (__bf16*)(ws + 108800000);                      //     524,288 B
    __bf16* radp  = (__bf16*)(ws + 108800000 + 524288);             //  12,812,288 B
    __bf16* WrbfT = (__bf16*)(ws + 108800000 + 524288 + 12812288);  //      65,536 B

    constexpr int GM = (NE + 127) / 128;  // 782

    k0<<<2088, 256, 0, stream>>>(mM, Wdb, rad, Wrbf, Wbil, mB, WdbT, radp, WrbfT, WbilT);
    k1<<<dim3(4, GM), 256, 0, stream>>>(mB, WdbT, radp, WrbfT, s_rbf, x1);
    k2<<<GM, 256, 0, stream>>>(x1, Wdown, x2);
    k3<<<NT / 64, 256, 0, stream>>>(cir, Wcbf, s_cbf, trip_in, x2, tt);
    k4a<<<NE / 32, 256, 0, stream>>>(tt, sph, t2q, smk);
    k4b<<<NE / 32, 256, 0, stream>>>(smk, sphW1, WbilT, s_sbf, xx);
    k5<<<dim3(GM, 4), 256, 0, stream>>>(xx, Wca, Wac, swp, (float*)d_out);
}